// Round 3
// baseline (226.007 us; speedup 1.0000x reference)
//
#include <hip/hip_runtime.h>
#include <cstdint>
#include <cstddef>

#define NTH 256
#define NGT 128
#define BATCH 16
#define NC 80
#define G 16                  // GTs per scan block
#define NCHUNK (NGT / G)      // 8
#define HW0 25600
#define HW1 6400
#define HW2 1600
#define SL0 4                 // hw slices for level 0
#define MAXSL 4
#define NLOSS_BLK 384         // loss blocks: (3 levels * 16 batch * 8 chunks)

// ws layout (bytes). part/partl slots are all written before read; the one
// counter is zeroed by scan_kernel (plain store, made visible by the
// kernel-boundary flush) so no extra zeroing dispatch is needed.
#define PART_OFF  0
#define PART_BYTES (3 * BATCH * NGT * MAXSL * 8)   // 196608
#define PARTL_OFF PART_BYTES
#define PARTL_BYTES (NLOSS_BLK * 3 * sizeof(float))
#define CTR_OFF   (PARTL_OFF + PARTL_BYTES)
#define WS_NEEDED ((size_t)CTR_OFF + 4)

__device__ __forceinline__ unsigned long long umin64(unsigned long long a, unsigned long long b) {
    return a < b ? a : b;
}

// u64 key (d2 bits << 32 | idx): min == min-d2 with first-index tie-break,
// exactly matching jnp.argmin (d2 >= 0 so float-bit order == integer order).
#define EVAL(px, py, idx_) do {                                                   \
    _Pragma("unroll")                                                             \
    for (int g = 0; g < G; ++g) {                                                 \
        float dx = gx[g] - (px), dy = gy[g] - (py);                               \
        float d2 = dx * dx + dy * dy;                                             \
        unsigned long long key =                                                  \
            ((unsigned long long)__float_as_uint(d2) << 32) | (unsigned)(idx_);   \
        kmin[g] = umin64(kmin[g], key);                                           \
    } } while (0)

// Scan: one block per (level, batch, hw-slice, chunk-of-16-GTs).
// Byte-identical hot path to R2 (proven); only addition is the one-thread
// plain store zeroing the completion counter for the next dispatch.
__global__ __launch_bounds__(NTH) void scan_kernel(
    const float* __restrict__ reg0, const float* __restrict__ reg1, const float* __restrict__ reg2,
    const float* __restrict__ gt_boxes,
    unsigned long long* __restrict__ part,
    unsigned int* __restrict__ ctr)
{
    if (blockIdx.x == 0 && threadIdx.x == 0) *ctr = 0u;

    int x = blockIdx.x;
    int lvl, b, slice, chunk, HW, nsl;
    const float* reg;
    if (x < BATCH * SL0 * NCHUNK) {                         // 512 lvl-0 blocks
        lvl = 0; b = x / (SL0 * NCHUNK);
        int r = x % (SL0 * NCHUNK);
        slice = r / NCHUNK; chunk = r % NCHUNK;
        HW = HW0; nsl = SL0; reg = reg0;
    } else if (x < BATCH * SL0 * NCHUNK + BATCH * NCHUNK) { // 128 lvl-1 blocks
        int y = x - BATCH * SL0 * NCHUNK;
        lvl = 1; b = y / NCHUNK; chunk = y % NCHUNK; slice = 0;
        HW = HW1; nsl = 1; reg = reg1;
    } else {                                                // 128 lvl-2 blocks
        int y = x - BATCH * SL0 * NCHUNK - BATCH * NCHUNK;
        lvl = 2; b = y / NCHUNK; chunk = y % NCHUNK; slice = 0;
        HW = HW2; nsl = 1; reg = reg2;
    }

    const int seg = HW / nsl;
    const int e0 = slice * seg, e1 = e0 + seg;
    const int tid = threadIdx.x, wave = tid >> 6, lane = tid & 63;
    const int n0 = chunk * G;

    float gx[G], gy[G];
#pragma unroll
    for (int g = 0; g < G; ++g) {
        const float* gb = gt_boxes + (size_t)(b * NGT + n0 + g) * 4;
        gx[g] = gb[0]; gy[g] = gb[1];
    }

    unsigned long long kmin[G];
#pragma unroll
    for (int g = 0; g < G; ++g) kmin[g] = ~0ull;

    const float4* rows = reinterpret_cast<const float4*>(reg) + (size_t)b * HW;
#pragma unroll 2
    for (int i = e0 + tid; i < e1; i += NTH) {
        float4 p = rows[i];
        EVAL(p.x, p.y, i);
    }

#pragma unroll
    for (int g = 0; g < G; ++g) {
#pragma unroll
        for (int off = 32; off >= 1; off >>= 1) {
            unsigned long long o = __shfl_down(kmin[g], off, 64);
            kmin[g] = umin64(kmin[g], o);
        }
    }

    __shared__ unsigned long long smem[G][4];
    if (lane == 0) {
#pragma unroll
        for (int g = 0; g < G; ++g) smem[g][wave] = kmin[g];
    }
    __syncthreads();

    if (tid < G) {
        unsigned long long key = umin64(umin64(smem[tid][0], smem[tid][1]),
                                        umin64(smem[tid][2], smem[tid][3]));
        part[((size_t)(lvl * BATCH + b) * NGT + n0 + tid) * MAXSL + slice] = key;
    }
}

// Loss + finalize: 384 blocks x 1024 threads; wave w handles GT (chunk*16+w)
// of its (lvl,b). Block reduces 16 (ce,l1,w) triples in LDS, writes ONE
// partial triple, then release-fence + one atomic on a single counter
// (384 staggered arrivals ~ 1-2 us tail — NOT the 18K-atomic disaster).
// The 384th arrival acquire-fences and tree-reduces all triples -> out.
__global__ __launch_bounds__(1024) void loss_fin_kernel(
    const float* __restrict__ cls0, const float* __restrict__ cls1, const float* __restrict__ cls2,
    const float* __restrict__ reg0, const float* __restrict__ reg1, const float* __restrict__ reg2,
    const float* __restrict__ gt_boxes, const int* __restrict__ gt_labels,
    const unsigned long long* __restrict__ part, float* __restrict__ partl,
    unsigned int* __restrict__ ctr, float* __restrict__ out)
{
    const int tid = threadIdx.x;
    const int wave = tid >> 6;      // 0..15
    const int lane = tid & 63;
    const int x = blockIdx.x;       // 0..383
    const int lvl = x >> 7;         // x / 128
    const int r = x & 127;
    const int b = r >> 3;
    const int chunk = r & 7;
    const int n = chunk * G + wave;

    const float* cls; const float* reg; int HW, S;
    if (lvl == 0)      { cls = cls0; reg = reg0; HW = HW0; S = SL0; }
    else if (lvl == 1) { cls = cls1; reg = reg1; HW = HW1; S = 1; }
    else               { cls = cls2; reg = reg2; HW = HW2; S = 1; }

    const int gid = (lvl * BATCH + b) * NGT + n;
    const unsigned long long* p = part + (size_t)gid * MAXSL;
    unsigned long long key = p[0];
    for (int s = 1; s < S; ++s) key = umin64(key, p[s]);

    int match = (int)(unsigned)(key & 0xffffffffu);
    float d2min = __uint_as_float((unsigned)(key >> 32));
    bool valid = d2min < 6.25f;  // sqrt(d2) < 2.5

    const int label = gt_labels[b * NGT + n];
    const float* c = cls + ((size_t)b * HW + match) * NC;

    // 80-class log-softmax across the wave
    float x1 = c[lane];
    float x2 = (lane < NC - 64) ? c[64 + lane] : -INFINITY;
    float mx = fmaxf(x1, x2);
#pragma unroll
    for (int off = 32; off >= 1; off >>= 1) mx = fmaxf(mx, __shfl_xor(mx, off, 64));
    float s = expf(x1 - mx) + ((lane < NC - 64) ? expf(x2 - mx) : 0.0f);
#pragma unroll
    for (int off = 32; off >= 1; off >>= 1) s += __shfl_xor(s, off, 64);

    __shared__ float tr[3][16];
    __shared__ int lastF;
    if (lane == 0) {
        float ce = 0.0f, l1 = 0.0f, w = 0.0f;
        if (valid) {
            float xlab = c[label];
            ce = -(xlab - mx - logf(s));
            const float* gb = gt_boxes + (size_t)(b * NGT + n) * 4;
            const float* gr = reg + ((size_t)b * HW + match) * 4;
            l1 = fabsf(gr[0] - gb[0]) + fabsf(gr[1] - gb[1]) +
                 fabsf(gr[2] - gb[2]) + fabsf(gr[3] - gb[3]);
            w = 1.0f;
        }
        tr[0][wave] = ce; tr[1][wave] = l1; tr[2][wave] = w;
    }
    __syncthreads();

    if (tid == 0) {
        float ce = 0.0f, l1 = 0.0f, w = 0.0f;
#pragma unroll
        for (int i = 0; i < 16; ++i) { ce += tr[0][i]; l1 += tr[1][i]; w += tr[2][i]; }
        float* o = partl + (size_t)x * 3;
        o[0] = ce; o[1] = l1; o[2] = w;
        __threadfence();   // release the triple before announcing completion
        lastF = (atomicAdd(ctr, 1u) == NLOSS_BLK - 1) ? 1 : 0;
    }
    __syncthreads();
    if (!lastF) return;

    // ---- final reduce (last block only): deterministic tree over 384 triples ----
    __threadfence();       // acquire all other blocks' triples
    float ce = 0.0f, l1 = 0.0f, w = 0.0f;
    for (int i = tid; i < NLOSS_BLK; i += 1024) {   // one element for tid<384
        const float* o = partl + (size_t)i * 3;
        ce += o[0]; l1 += o[1]; w += o[2];
    }
#pragma unroll
    for (int off = 32; off >= 1; off >>= 1) {
        ce += __shfl_xor(ce, off, 64);
        l1 += __shfl_xor(l1, off, 64);
        w  += __shfl_xor(w,  off, 64);
    }
    __shared__ float sm[3][16];
    if (lane == 0) { sm[0][wave] = ce; sm[1][wave] = l1; sm[2][wave] = w; }
    __syncthreads();
    if (tid == 0) {
        float tce = 0.0f, tl1 = 0.0f, tw = 0.0f;
#pragma unroll
        for (int i = 0; i < 16; ++i) { tce += sm[0][i]; tl1 += sm[1][i]; tw += sm[2][i]; }
        float denom = fmaxf(tw, 1.0f);
        out[0] = tce / denom;
        out[1] = tl1 / denom;
        out[2] = tw;
    }
}

extern "C" void kernel_launch(void* const* d_in, const int* in_sizes, int n_in,
                              void* d_out, int out_size, void* d_ws, size_t ws_size,
                              hipStream_t stream) {
    // Map inputs BY SIZE (dict order interleaves cls/reg; all sizes distinct).
    const float* cls0 = nullptr; const float* cls1 = nullptr; const float* cls2 = nullptr;
    const float* reg0 = nullptr; const float* reg1 = nullptr; const float* reg2 = nullptr;
    const float* gt_boxes = nullptr; const int* gt_labels = nullptr;
    for (int i = 0; i < n_in; ++i) {
        switch (in_sizes[i]) {
            case BATCH * HW0 * NC: cls0 = (const float*)d_in[i]; break;
            case BATCH * HW1 * NC: cls1 = (const float*)d_in[i]; break;
            case BATCH * HW2 * NC: cls2 = (const float*)d_in[i]; break;
            case BATCH * HW0 * 4:  reg0 = (const float*)d_in[i]; break;
            case BATCH * HW1 * 4:  reg1 = (const float*)d_in[i]; break;
            case BATCH * HW2 * 4:  reg2 = (const float*)d_in[i]; break;
            case BATCH * NGT * 4:  gt_boxes = (const float*)d_in[i]; break;
            case BATCH * NGT:      gt_labels = (const int*)d_in[i]; break;
            default: break;
        }
    }

    char* ws = (char*)d_ws;
    unsigned long long* part = (unsigned long long*)(ws + PART_OFF);
    float* partl             = (float*)(ws + PARTL_OFF);
    unsigned int* ctr        = (unsigned int*)(ws + CTR_OFF);
    const int scan_grid = BATCH * SL0 * NCHUNK + 2 * BATCH * NCHUNK;  // 768

    scan_kernel<<<scan_grid, NTH, 0, stream>>>(
        reg0, reg1, reg2, gt_boxes, part, ctr);

    loss_fin_kernel<<<NLOSS_BLK, 1024, 0, stream>>>(
        cls0, cls1, cls2, reg0, reg1, reg2, gt_boxes, gt_labels,
        part, partl, ctr, (float*)d_out);
}

// Round 4
// 223.434 us; speedup vs baseline: 1.0115x; 1.0115x over previous
//
#include <hip/hip_runtime.h>
#include <cstdint>
#include <cstddef>

#define NTH 256
#define NGT 128
#define BATCH 16
#define NC 80
#define G 16                  // GTs per scan block
#define NCHUNK (NGT / G)      // 8
#define HW0 25600
#define HW1 6400
#define HW2 1600
#define SL0 8                 // hw slices for level 0 (R4: 4->8 for latency hiding)
#define MAXSL 8
#define NLOSS_BLK (3 * BATCH * NGT / 4)   // 1536 loss blocks (4 GTs each)

// ws layout (bytes) — no counters, no atomics, no fences (R1/R3 post-mortem:
// any cross-block completion protocol costs more than a kernel boundary).
// Every part/partl slot read is written first within the producing dispatch.
#define PART_OFF  0
#define PART_BYTES (3 * BATCH * NGT * MAXSL * 8)   // 393216
#define PARTL_OFF PART_BYTES
#define PARTL_BYTES (NLOSS_BLK * 3 * sizeof(float))
#define WS_NEEDED ((size_t)PARTL_OFF + (size_t)PARTL_BYTES)

__device__ __forceinline__ unsigned long long umin64(unsigned long long a, unsigned long long b) {
    return a < b ? a : b;
}

// u64 key (d2 bits << 32 | idx): min == min-d2 with first-index tie-break,
// exactly matching jnp.argmin (d2 >= 0 so float-bit order == integer order).
#define EVAL(px, py, idx_) do {                                                   \
    _Pragma("unroll")                                                             \
    for (int g = 0; g < G; ++g) {                                                 \
        float dx = gx[g] - (px), dy = gy[g] - (py);                               \
        float d2 = dx * dx + dy * dy;                                             \
        unsigned long long key =                                                  \
            ((unsigned long long)__float_as_uint(d2) << 32) | (unsigned)(idx_);   \
        kmin[g] = umin64(kmin[g], key);                                           \
    } } while (0)

// Scan: one block per (level, batch, hw-slice, chunk-of-16-GTs).
// Reads raw reg rows as coalesced float4 (16 B/lane); chunk blocks sharing a
// (b,slice) region re-read L2/L3-resident data (reg total = 8.6 MB).
// NO cross-block sync: partial keys go to `part`, combined by loss_kernel
// after the kernel boundary (the cheap global sync on this chip).
__global__ __launch_bounds__(NTH) void scan_kernel(
    const float* __restrict__ reg0, const float* __restrict__ reg1, const float* __restrict__ reg2,
    const float* __restrict__ gt_boxes,
    unsigned long long* __restrict__ part)
{
    int x = blockIdx.x;
    int lvl, b, slice, chunk, HW, nsl;
    const float* reg;
    if (x < BATCH * SL0 * NCHUNK) {                         // 1024 lvl-0 blocks
        lvl = 0; b = x / (SL0 * NCHUNK);
        int r = x % (SL0 * NCHUNK);
        slice = r / NCHUNK; chunk = r % NCHUNK;
        HW = HW0; nsl = SL0; reg = reg0;
    } else if (x < BATCH * SL0 * NCHUNK + BATCH * NCHUNK) { // 128 lvl-1 blocks
        int y = x - BATCH * SL0 * NCHUNK;
        lvl = 1; b = y / NCHUNK; chunk = y % NCHUNK; slice = 0;
        HW = HW1; nsl = 1; reg = reg1;
    } else {                                                // 128 lvl-2 blocks
        int y = x - BATCH * SL0 * NCHUNK - BATCH * NCHUNK;
        lvl = 2; b = y / NCHUNK; chunk = y % NCHUNK; slice = 0;
        HW = HW2; nsl = 1; reg = reg2;
    }

    const int seg = HW / nsl;
    const int e0 = slice * seg, e1 = e0 + seg;
    const int tid = threadIdx.x, wave = tid >> 6, lane = tid & 63;
    const int n0 = chunk * G;

    float gx[G], gy[G];
#pragma unroll
    for (int g = 0; g < G; ++g) {
        const float* gb = gt_boxes + (size_t)(b * NGT + n0 + g) * 4;
        gx[g] = gb[0]; gy[g] = gb[1];
    }

    unsigned long long kmin[G];
#pragma unroll
    for (int g = 0; g < G; ++g) kmin[g] = ~0ull;

    const float4* rows = reinterpret_cast<const float4*>(reg) + (size_t)b * HW;
#pragma unroll 2
    for (int i = e0 + tid; i < e1; i += NTH) {
        float4 p = rows[i];
        EVAL(p.x, p.y, i);
    }

#pragma unroll
    for (int g = 0; g < G; ++g) {
#pragma unroll
        for (int off = 32; off >= 1; off >>= 1) {
            unsigned long long o = __shfl_down(kmin[g], off, 64);
            kmin[g] = umin64(kmin[g], o);
        }
    }

    __shared__ unsigned long long smem[G][4];
    if (lane == 0) {
#pragma unroll
        for (int g = 0; g < G; ++g) smem[g][wave] = kmin[g];
    }
    __syncthreads();

    if (tid < G) {
        unsigned long long key = umin64(umin64(smem[tid][0], smem[tid][1]),
                                        umin64(smem[tid][2], smem[tid][3]));
        part[((size_t)(lvl * BATCH + b) * NGT + n0 + tid) * MAXSL + slice] = key;
    }
}

// Loss: one wave per (level, batch, gt); 4 waves per block. NO ATOMICS —
// block reduces its 4 (ce,l1,w) triples in LDS and writes ONE partial triple
// to a distinct slot.
__global__ __launch_bounds__(NTH) void loss_kernel(
    const float* __restrict__ cls0, const float* __restrict__ cls1, const float* __restrict__ cls2,
    const float* __restrict__ reg0, const float* __restrict__ reg1, const float* __restrict__ reg2,
    const float* __restrict__ gt_boxes, const int* __restrict__ gt_labels,
    const unsigned long long* __restrict__ part, float* __restrict__ partl)
{
    const int wave = threadIdx.x >> 6;
    const int lane = threadIdx.x & 63;
    const int gid = blockIdx.x * 4 + wave;     // 0..6143
    const int lvl = gid / (BATCH * NGT);
    const int r = gid % (BATCH * NGT);
    const int b = r / NGT, n = r % NGT;

    const float* cls; const float* reg; int HW, S;
    if (lvl == 0)      { cls = cls0; reg = reg0; HW = HW0; S = SL0; }
    else if (lvl == 1) { cls = cls1; reg = reg1; HW = HW1; S = 1; }
    else               { cls = cls2; reg = reg2; HW = HW2; S = 1; }

    const unsigned long long* p = part + (size_t)gid * MAXSL;
    unsigned long long key = p[0];
    for (int s = 1; s < S; ++s) key = umin64(key, p[s]);

    int match = (int)(unsigned)(key & 0xffffffffu);
    float d2min = __uint_as_float((unsigned)(key >> 32));
    bool valid = d2min < 6.25f;  // sqrt(d2) < 2.5

    const int label = gt_labels[b * NGT + n];
    const float* c = cls + ((size_t)b * HW + match) * NC;

    // 80-class log-softmax across the wave
    float x1 = c[lane];
    float x2 = (lane < NC - 64) ? c[64 + lane] : -INFINITY;
    float mx = fmaxf(x1, x2);
#pragma unroll
    for (int off = 32; off >= 1; off >>= 1) mx = fmaxf(mx, __shfl_xor(mx, off, 64));
    float s = expf(x1 - mx) + ((lane < NC - 64) ? expf(x2 - mx) : 0.0f);
#pragma unroll
    for (int off = 32; off >= 1; off >>= 1) s += __shfl_xor(s, off, 64);

    __shared__ float ce_s[4], l1_s[4], w_s[4];
    if (lane == 0) {
        float ce = 0.0f, l1 = 0.0f, w = 0.0f;
        if (valid) {
            float xlab = c[label];
            ce = -(xlab - mx - logf(s));
            const float* gb = gt_boxes + (size_t)(b * NGT + n) * 4;
            const float* gr = reg + ((size_t)b * HW + match) * 4;
            l1 = fabsf(gr[0] - gb[0]) + fabsf(gr[1] - gb[1]) +
                 fabsf(gr[2] - gb[2]) + fabsf(gr[3] - gb[3]);
            w = 1.0f;
        }
        ce_s[wave] = ce; l1_s[wave] = l1; w_s[wave] = w;
    }
    __syncthreads();

    if (threadIdx.x == 0) {
        float* o = partl + (size_t)blockIdx.x * 3;
        o[0] = ce_s[0] + ce_s[1] + ce_s[2] + ce_s[3];
        o[1] = l1_s[0] + l1_s[1] + l1_s[2] + l1_s[3];
        o[2] = w_s[0] + w_s[1] + w_s[2] + w_s[3];
    }
}

// Deterministic tree reduction of the 1536 partial triples; writes outputs.
__global__ __launch_bounds__(NTH) void finalize_kernel(
    const float* __restrict__ partl, float* __restrict__ out)
{
    const int tid = threadIdx.x, wave = tid >> 6, lane = tid & 63;
    float ce = 0.0f, l1 = 0.0f, w = 0.0f;
    for (int i = tid; i < NLOSS_BLK; i += NTH) {
        ce += partl[(size_t)i * 3 + 0];
        l1 += partl[(size_t)i * 3 + 1];
        w  += partl[(size_t)i * 3 + 2];
    }
#pragma unroll
    for (int off = 32; off >= 1; off >>= 1) {
        ce += __shfl_xor(ce, off, 64);
        l1 += __shfl_xor(l1, off, 64);
        w  += __shfl_xor(w,  off, 64);
    }
    __shared__ float sm[3][4];
    if (lane == 0) { sm[0][wave] = ce; sm[1][wave] = l1; sm[2][wave] = w; }
    __syncthreads();
    if (tid == 0) {
        float tce = sm[0][0] + sm[0][1] + sm[0][2] + sm[0][3];
        float tl1 = sm[1][0] + sm[1][1] + sm[1][2] + sm[1][3];
        float tw  = sm[2][0] + sm[2][1] + sm[2][2] + sm[2][3];
        float denom = fmaxf(tw, 1.0f);
        out[0] = tce / denom;
        out[1] = tl1 / denom;
        out[2] = tw;
    }
}

extern "C" void kernel_launch(void* const* d_in, const int* in_sizes, int n_in,
                              void* d_out, int out_size, void* d_ws, size_t ws_size,
                              hipStream_t stream) {
    // Map inputs BY SIZE (dict order interleaves cls/reg; all sizes distinct).
    const float* cls0 = nullptr; const float* cls1 = nullptr; const float* cls2 = nullptr;
    const float* reg0 = nullptr; const float* reg1 = nullptr; const float* reg2 = nullptr;
    const float* gt_boxes = nullptr; const int* gt_labels = nullptr;
    for (int i = 0; i < n_in; ++i) {
        switch (in_sizes[i]) {
            case BATCH * HW0 * NC: cls0 = (const float*)d_in[i]; break;
            case BATCH * HW1 * NC: cls1 = (const float*)d_in[i]; break;
            case BATCH * HW2 * NC: cls2 = (const float*)d_in[i]; break;
            case BATCH * HW0 * 4:  reg0 = (const float*)d_in[i]; break;
            case BATCH * HW1 * 4:  reg1 = (const float*)d_in[i]; break;
            case BATCH * HW2 * 4:  reg2 = (const float*)d_in[i]; break;
            case BATCH * NGT * 4:  gt_boxes = (const float*)d_in[i]; break;
            case BATCH * NGT:      gt_labels = (const int*)d_in[i]; break;
            default: break;
        }
    }

    char* ws = (char*)d_ws;
    unsigned long long* part = (unsigned long long*)(ws + PART_OFF);
    float* partl             = (float*)(ws + PARTL_OFF);
    const int scan_grid = BATCH * SL0 * NCHUNK + 2 * BATCH * NCHUNK;  // 1280

    scan_kernel<<<scan_grid, NTH, 0, stream>>>(
        reg0, reg1, reg2, gt_boxes, part);

    loss_kernel<<<NLOSS_BLK, NTH, 0, stream>>>(
        cls0, cls1, cls2, reg0, reg1, reg2, gt_boxes, gt_labels, part, partl);

    finalize_kernel<<<1, NTH, 0, stream>>>(partl, (float*)d_out);
}

// Round 5
// 217.037 us; speedup vs baseline: 1.0413x; 1.0295x over previous
//
#include <hip/hip_runtime.h>
#include <cstdint>
#include <cstddef>

#define NTH 256
#define NGT 128
#define BATCH 16
#define NC 80
#define G 16                  // GTs per scan block
#define NCHUNK (NGT / G)      // 8
#define HW0 25600
#define HW1 6400
#define HW2 1600
#define SL0 4                 // hw slices for level 0 (R2-proven; 8 regressed)
#define MAXSL 4
#define NLOSS_BLK (3 * BATCH * NGT / 4)   // 1536 loss blocks (4 GTs each)

// ws layout (bytes) — no counters, no atomics, no fences (R1/R3 post-mortem:
// any cross-block completion protocol costs more than a kernel boundary).
// Every part/partl slot read is written first within the producing dispatch.
#define PART_OFF  0
#define PART_BYTES (3 * BATCH * NGT * MAXSL * 8)   // 196608
#define PARTL_OFF PART_BYTES
#define PARTL_BYTES (NLOSS_BLK * 3 * sizeof(float))
#define WS_NEEDED ((size_t)PARTL_OFF + (size_t)PARTL_BYTES)

__device__ __forceinline__ unsigned long long umin64(unsigned long long a, unsigned long long b) {
    return a < b ? a : b;
}

// u64 key (d2 bits << 32 | idx): min == min-d2 with first-index tie-break,
// exactly matching jnp.argmin (d2 >= 0 so float-bit order == integer order).
#define EVAL(px, py, idx_) do {                                                   \
    _Pragma("unroll")                                                             \
    for (int g = 0; g < G; ++g) {                                                 \
        float dx = gx[g] - (px), dy = gy[g] - (py);                               \
        float d2 = dx * dx + dy * dy;                                             \
        unsigned long long key =                                                  \
            ((unsigned long long)__float_as_uint(d2) << 32) | (unsigned)(idx_);   \
        kmin[g] = umin64(kmin[g], key);                                           \
    } } while (0)

// Scan: one block per (level, batch, hw-slice, chunk-of-16-GTs).
// Reads raw reg rows as coalesced float4 (16 B/lane); the 8 chunk blocks that
// share a (b,slice) region re-read L2/L3-resident data (reg total = 8.6 MB).
// NO cross-block sync: partial keys go to `part`, combined by loss_kernel
// after the kernel boundary (the cheap global sync on this chip).
__global__ __launch_bounds__(NTH) void scan_kernel(
    const float* __restrict__ reg0, const float* __restrict__ reg1, const float* __restrict__ reg2,
    const float* __restrict__ gt_boxes,
    unsigned long long* __restrict__ part)
{
    int x = blockIdx.x;
    int lvl, b, slice, chunk, HW, nsl;
    const float* reg;
    if (x < BATCH * SL0 * NCHUNK) {                         // 512 lvl-0 blocks
        lvl = 0; b = x / (SL0 * NCHUNK);
        int r = x % (SL0 * NCHUNK);
        slice = r / NCHUNK; chunk = r % NCHUNK;
        HW = HW0; nsl = SL0; reg = reg0;
    } else if (x < BATCH * SL0 * NCHUNK + BATCH * NCHUNK) { // 128 lvl-1 blocks
        int y = x - BATCH * SL0 * NCHUNK;
        lvl = 1; b = y / NCHUNK; chunk = y % NCHUNK; slice = 0;
        HW = HW1; nsl = 1; reg = reg1;
    } else {                                                // 128 lvl-2 blocks
        int y = x - BATCH * SL0 * NCHUNK - BATCH * NCHUNK;
        lvl = 2; b = y / NCHUNK; chunk = y % NCHUNK; slice = 0;
        HW = HW2; nsl = 1; reg = reg2;
    }

    const int seg = HW / nsl;
    const int e0 = slice * seg, e1 = e0 + seg;
    const int tid = threadIdx.x, wave = tid >> 6, lane = tid & 63;
    const int n0 = chunk * G;

    float gx[G], gy[G];
#pragma unroll
    for (int g = 0; g < G; ++g) {
        const float* gb = gt_boxes + (size_t)(b * NGT + n0 + g) * 4;
        gx[g] = gb[0]; gy[g] = gb[1];
    }

    unsigned long long kmin[G];
#pragma unroll
    for (int g = 0; g < G; ++g) kmin[g] = ~0ull;

    const float4* rows = reinterpret_cast<const float4*>(reg) + (size_t)b * HW;
#pragma unroll 2
    for (int i = e0 + tid; i < e1; i += NTH) {
        float4 p = rows[i];
        EVAL(p.x, p.y, i);
    }

#pragma unroll
    for (int g = 0; g < G; ++g) {
#pragma unroll
        for (int off = 32; off >= 1; off >>= 1) {
            unsigned long long o = __shfl_down(kmin[g], off, 64);
            kmin[g] = umin64(kmin[g], o);
        }
    }

    __shared__ unsigned long long smem[G][4];
    if (lane == 0) {
#pragma unroll
        for (int g = 0; g < G; ++g) smem[g][wave] = kmin[g];
    }
    __syncthreads();

    if (tid < G) {
        unsigned long long key = umin64(umin64(smem[tid][0], smem[tid][1]),
                                        umin64(smem[tid][2], smem[tid][3]));
        part[((size_t)(lvl * BATCH + b) * NGT + n0 + tid) * MAXSL + slice] = key;
    }
}

// Loss: one wave per (level, batch, gt); 4 waves per block. NO ATOMICS —
// block reduces its 4 (ce,l1,w) triples in LDS and writes ONE partial triple
// to a distinct slot.
__global__ __launch_bounds__(NTH) void loss_kernel(
    const float* __restrict__ cls0, const float* __restrict__ cls1, const float* __restrict__ cls2,
    const float* __restrict__ reg0, const float* __restrict__ reg1, const float* __restrict__ reg2,
    const float* __restrict__ gt_boxes, const int* __restrict__ gt_labels,
    const unsigned long long* __restrict__ part, float* __restrict__ partl)
{
    const int wave = threadIdx.x >> 6;
    const int lane = threadIdx.x & 63;
    const int gid = blockIdx.x * 4 + wave;     // 0..6143
    const int lvl = gid / (BATCH * NGT);
    const int r = gid % (BATCH * NGT);
    const int b = r / NGT, n = r % NGT;

    const float* cls; const float* reg; int HW, S;
    if (lvl == 0)      { cls = cls0; reg = reg0; HW = HW0; S = SL0; }
    else if (lvl == 1) { cls = cls1; reg = reg1; HW = HW1; S = 1; }
    else               { cls = cls2; reg = reg2; HW = HW2; S = 1; }

    const unsigned long long* p = part + (size_t)gid * MAXSL;
    unsigned long long key = p[0];
    for (int s = 1; s < S; ++s) key = umin64(key, p[s]);

    int match = (int)(unsigned)(key & 0xffffffffu);
    float d2min = __uint_as_float((unsigned)(key >> 32));
    bool valid = d2min < 6.25f;  // sqrt(d2) < 2.5

    const int label = gt_labels[b * NGT + n];
    const float* c = cls + ((size_t)b * HW + match) * NC;

    // 80-class log-softmax across the wave
    float x1 = c[lane];
    float x2 = (lane < NC - 64) ? c[64 + lane] : -INFINITY;
    float mx = fmaxf(x1, x2);
#pragma unroll
    for (int off = 32; off >= 1; off >>= 1) mx = fmaxf(mx, __shfl_xor(mx, off, 64));
    float s = expf(x1 - mx) + ((lane < NC - 64) ? expf(x2 - mx) : 0.0f);
#pragma unroll
    for (int off = 32; off >= 1; off >>= 1) s += __shfl_xor(s, off, 64);

    __shared__ float ce_s[4], l1_s[4], w_s[4];
    if (lane == 0) {
        float ce = 0.0f, l1 = 0.0f, w = 0.0f;
        if (valid) {
            float xlab = c[label];
            ce = -(xlab - mx - logf(s));
            const float* gb = gt_boxes + (size_t)(b * NGT + n) * 4;
            const float* gr = reg + ((size_t)b * HW + match) * 4;
            l1 = fabsf(gr[0] - gb[0]) + fabsf(gr[1] - gb[1]) +
                 fabsf(gr[2] - gb[2]) + fabsf(gr[3] - gb[3]);
            w = 1.0f;
        }
        ce_s[wave] = ce; l1_s[wave] = l1; w_s[wave] = w;
    }
    __syncthreads();

    if (threadIdx.x == 0) {
        float* o = partl + (size_t)blockIdx.x * 3;
        o[0] = ce_s[0] + ce_s[1] + ce_s[2] + ce_s[3];
        o[1] = l1_s[0] + l1_s[1] + l1_s[2] + l1_s[3];
        o[2] = w_s[0] + w_s[1] + w_s[2] + w_s[3];
    }
}

// Deterministic tree reduction of the 1536 partial triples; writes outputs.
__global__ __launch_bounds__(NTH) void finalize_kernel(
    const float* __restrict__ partl, float* __restrict__ out)
{
    const int tid = threadIdx.x, wave = tid >> 6, lane = tid & 63;
    float ce = 0.0f, l1 = 0.0f, w = 0.0f;
    for (int i = tid; i < NLOSS_BLK; i += NTH) {
        ce += partl[(size_t)i * 3 + 0];
        l1 += partl[(size_t)i * 3 + 1];
        w  += partl[(size_t)i * 3 + 2];
    }
#pragma unroll
    for (int off = 32; off >= 1; off >>= 1) {
        ce += __shfl_xor(ce, off, 64);
        l1 += __shfl_xor(l1, off, 64);
        w  += __shfl_xor(w,  off, 64);
    }
    __shared__ float sm[3][4];
    if (lane == 0) { sm[0][wave] = ce; sm[1][wave] = l1; sm[2][wave] = w; }
    __syncthreads();
    if (tid == 0) {
        float tce = sm[0][0] + sm[0][1] + sm[0][2] + sm[0][3];
        float tl1 = sm[1][0] + sm[1][1] + sm[1][2] + sm[1][3];
        float tw  = sm[2][0] + sm[2][1] + sm[2][2] + sm[2][3];
        float denom = fmaxf(tw, 1.0f);
        out[0] = tce / denom;
        out[1] = tl1 / denom;
        out[2] = tw;
    }
}

extern "C" void kernel_launch(void* const* d_in, const int* in_sizes, int n_in,
                              void* d_out, int out_size, void* d_ws, size_t ws_size,
                              hipStream_t stream) {
    // Map inputs BY SIZE (dict order interleaves cls/reg; all sizes distinct).
    const float* cls0 = nullptr; const float* cls1 = nullptr; const float* cls2 = nullptr;
    const float* reg0 = nullptr; const float* reg1 = nullptr; const float* reg2 = nullptr;
    const float* gt_boxes = nullptr; const int* gt_labels = nullptr;
    for (int i = 0; i < n_in; ++i) {
        switch (in_sizes[i]) {
            case BATCH * HW0 * NC: cls0 = (const float*)d_in[i]; break;
            case BATCH * HW1 * NC: cls1 = (const float*)d_in[i]; break;
            case BATCH * HW2 * NC: cls2 = (const float*)d_in[i]; break;
            case BATCH * HW0 * 4:  reg0 = (const float*)d_in[i]; break;
            case BATCH * HW1 * 4:  reg1 = (const float*)d_in[i]; break;
            case BATCH * HW2 * 4:  reg2 = (const float*)d_in[i]; break;
            case BATCH * NGT * 4:  gt_boxes = (const float*)d_in[i]; break;
            case BATCH * NGT:      gt_labels = (const int*)d_in[i]; break;
            default: break;
        }
    }

    char* ws = (char*)d_ws;
    unsigned long long* part = (unsigned long long*)(ws + PART_OFF);
    float* partl             = (float*)(ws + PARTL_OFF);
    const int scan_grid = BATCH * SL0 * NCHUNK + 2 * BATCH * NCHUNK;  // 768

    scan_kernel<<<scan_grid, NTH, 0, stream>>>(
        reg0, reg1, reg2, gt_boxes, part);

    loss_kernel<<<NLOSS_BLK, NTH, 0, stream>>>(
        cls0, cls1, cls2, reg0, reg1, reg2, gt_boxes, gt_labels, part, partl);

    finalize_kernel<<<1, NTH, 0, stream>>>(partl, (float*)d_out);
}